// Round 12
// baseline (39.166 us; speedup 1.0000x reference)
//
#include <hip/hip_runtime.h>
#include <math.h>

#define Hd 512
#define Bn 8
#define Sn 8192
#define SB 256            // energy blocks per b (32 rows each)
#define PW (SB * 4)       // partials per b (one per wave)

typedef __attribute__((ext_vector_type(4))) float f32x4;

// ---------------------------------------------------------------------------
// K1: v[b,h] = sum_k hidden[b,k] * W[k,h], partitioned by h-columns.
// grid (16, Bn), block 512. IDENTICAL to round 7; launched 4x this round as
// a timing decomposition probe (idempotent).
// ---------------------------------------------------------------------------
__global__ __launch_bounds__(512) void k_proj(const float* __restrict__ hidden,
                                              const float* __restrict__ W,
                                              float* __restrict__ v) {
    const int hc = blockIdx.x;        // 0..15
    const int b  = blockIdx.y;
    const int t  = threadIdx.x;
    const int kg = t >> 5;            // 0..15 (k-group: 32 k's each)
    const int c  = t & 31;            // 0..31 (column within stripe)
    const int col = hc * 32 + c;

    __shared__ float hs[Hd];
    __shared__ float partial[16][32];

    hs[t] = hidden[b * Hd + t];
    __syncthreads();

    float acc = 0.f;
    const int k0 = kg * 32;
    #pragma unroll 16
    for (int i = 0; i < 32; ++i)
        acc += hs[k0 + i] * W[(size_t)(k0 + i) * Hd + col];
    partial[kg][c] = acc;
    __syncthreads();

    if (t < 32) {
        float s = partial[0][t];
        #pragma unroll
        for (int j = 1; j < 16; ++j) s += partial[j][t];
        v[b * Hd + hc * 32 + t] = s;
    }
}

// ---------------------------------------------------------------------------
// K2: e[b,s] = enc[b,s,:] . v[b,:]  + per-WAVE (max, sum-exp) partial.
// grid (SB, Bn), block 256 (4 waves); 8 rows per wave. IDENTICAL to round 7.
// ---------------------------------------------------------------------------
__global__ __launch_bounds__(256, 8) void k_energy(const float* __restrict__ enc,
                                                   const float* __restrict__ v,
                                                   float* __restrict__ e,
                                                   float2* __restrict__ partials) {
    const int sb   = blockIdx.x;
    const int b    = blockIdx.y;
    const int wave = threadIdx.x >> 6, lane = threadIdx.x & 63;

    const f32x4* vp = (const f32x4*)(v + b * Hd);
    const f32x4 v0 = vp[lane];
    const f32x4 v1 = vp[64 + lane];

    const int row0 = sb * 32 + wave * 8;
    const f32x4* base = (const f32x4*)(enc + ((size_t)b * Sn + row0) * Hd);

    float wA, wB;
    #pragma unroll
    for (int g = 0; g < 2; ++g) {
        const int rb = g * 4;
        float p[4];
        #pragma unroll
        for (int r = 0; r < 4; ++r) {
            const f32x4* rowp = base + (size_t)(rb + r) * (Hd / 4);
            const f32x4 a0 = __builtin_nontemporal_load(rowp + lane);
            const f32x4 a1 = __builtin_nontemporal_load(rowp + 64 + lane);
            p[r] = a0.x * v0.x + a0.y * v0.y + a0.z * v0.z + a0.w * v0.w
                 + a1.x * v1.x + a1.y * v1.y + a1.z * v1.z + a1.w * v1.w;
        }
        float s0 = p[0] + __shfl_xor(p[0], 1, 64);
        float s1 = p[1] + __shfl_xor(p[1], 1, 64);
        float s2 = p[2] + __shfl_xor(p[2], 1, 64);
        float s3 = p[3] + __shfl_xor(p[3], 1, 64);
        float t0 = (lane & 1) ? s1 : s0;
        float t1 = (lane & 1) ? s3 : s2;
        t0 += __shfl_xor(t0, 2, 64);
        t1 += __shfl_xor(t1, 2, 64);
        float w = (lane & 2) ? t1 : t0;
        w += __shfl_xor(w, 4, 64);
        w += __shfl_xor(w, 8, 64);
        w += __shfl_xor(w, 16, 64);
        w += __shfl_xor(w, 32, 64);
        if (g == 0) wA = w; else wB = w;
    }

    float m = fmaxf(wA, wB);
    m = fmaxf(m, __shfl_xor(m, 1, 64));
    m = fmaxf(m, __shfl_xor(m, 2, 64));
    float s = __expf(wA - m) + __expf(wB - m);
    s += __shfl_xor(s, 1, 64);
    s += __shfl_xor(s, 2, 64);

    if (lane < 8) e[(size_t)b * Sn + row0 + lane] = (lane < 4) ? wA : wB;
    if (lane == 0) partials[(size_t)b * PW + sb * 4 + wave] = make_float2(m, s);
}

// ---------------------------------------------------------------------------
// K3: out[b,j] = exp(e[b,j] - M_b) / L_b.  grid (16, Bn), block 512.
// IDENTICAL to round 7.
// ---------------------------------------------------------------------------
__global__ __launch_bounds__(512) void k_finalize(const float* __restrict__ e,
                                                  const float2* __restrict__ partials,
                                                  float* __restrict__ out) {
    const int b    = blockIdx.y;
    const int t    = threadIdx.x;
    const int lane = t & 63;

    const float2* pp = partials + (size_t)b * PW;
    float m[16], l[16];
    #pragma unroll
    for (int i = 0; i < 16; ++i) {
        const float2 q = pp[lane + 64 * i];
        m[i] = q.x; l[i] = q.y;
    }
    #pragma unroll
    for (int st = 8; st >= 1; st >>= 1) {
        #pragma unroll
        for (int i = 0; i < st; ++i) {
            const float Mn = fmaxf(m[i], m[i + st]);
            l[i] = l[i] * __expf(m[i] - Mn) + l[i + st] * __expf(m[i + st] - Mn);
            m[i] = Mn;
        }
    }
    float M = m[0], L = l[0];
    #pragma unroll
    for (int off = 32; off >= 1; off >>= 1) {
        const float Mo = __shfl_xor(M, off, 64);
        const float Lo = __shfl_xor(L, off, 64);
        const float Mn = fmaxf(M, Mo);
        L = L * __expf(M - Mn) + Lo * __expf(Mo - Mn);
        M = Mn;
    }
    const float inv = 1.0f / L;

    const size_t j = (size_t)b * Sn + blockIdx.x * 512 + t;
    out[j] = __expf(e[j] - M) * inv;
}

// ---------------------------------------------------------------------------
extern "C" void kernel_launch(void* const* d_in, const int* in_sizes, int n_in,
                              void* d_out, int out_size, void* d_ws, size_t ws_size,
                              hipStream_t stream) {
    const float* hidden = (const float*)d_in[0];   // [1,B,H]
    const float* enc    = (const float*)d_in[1];   // [B,S,H]
    const float* W      = (const float*)d_in[2];   // [H,H]
    // d_in[3] (bias) unused: softmax over s is shift-invariant.
    float* out = (float*)d_out;                    // [B,S] f32

    float*  v        = (float*)d_ws;               // Bn*Hd floats (16 KB)
    float2* partials = (float2*)(v + Bn * Hd);     // Bn*PW float2 (64 KB)
    float*  e        = (float*)(partials + (size_t)Bn * PW); // Bn*Sn floats

    // --- decomposition probe: 4 identical (idempotent) proj launches ---
    // dur = 32.75 + 3*(P+OH)  ->  P+OH = (dur - 32.75)/3
    k_proj    <<<dim3(16, Bn), 512, 0, stream>>>(hidden, W, v);
    k_proj    <<<dim3(16, Bn), 512, 0, stream>>>(hidden, W, v);
    k_proj    <<<dim3(16, Bn), 512, 0, stream>>>(hidden, W, v);
    k_proj    <<<dim3(16, Bn), 512, 0, stream>>>(hidden, W, v);
    k_energy  <<<dim3(SB, Bn), 256, 0, stream>>>(enc, v, e, partials);
    k_finalize<<<dim3(16, Bn), 512, 0, stream>>>(e, partials, out);
}

// Round 13
// 32.343 us; speedup vs baseline: 1.2110x; 1.2110x over previous
//
#include <hip/hip_runtime.h>
#include <math.h>

#define Hd 512
#define Bn 8
#define Sn 8192
#define SB 256            // energy blocks per b (32 rows each)
#define PW (SB * 4)       // partials per b (one per wave)

typedef __attribute__((ext_vector_type(4))) float f32x4;

// ---------------------------------------------------------------------------
// K1: v[b,h] = sum_k hidden[b,k] * W[k,h], partitioned by h-columns.
// grid (16, Bn), block 512 = 16 k-groups x 32 cols (32 k's per thread).
// Marginal cost measured (R12 probe): 2.14 us, node-overhead-dominated.
// ---------------------------------------------------------------------------
__global__ __launch_bounds__(512) void k_proj(const float* __restrict__ hidden,
                                              const float* __restrict__ W,
                                              float* __restrict__ v) {
    const int hc = blockIdx.x;        // 0..15
    const int b  = blockIdx.y;
    const int t  = threadIdx.x;
    const int kg = t >> 5;            // 0..15 (k-group: 32 k's each)
    const int c  = t & 31;            // 0..31 (column within stripe)
    const int col = hc * 32 + c;

    __shared__ float hs[Hd];
    __shared__ float partial[16][32];

    hs[t] = hidden[b * Hd + t];
    __syncthreads();

    float acc = 0.f;
    const int k0 = kg * 32;
    #pragma unroll 16
    for (int i = 0; i < 32; ++i)
        acc += hs[k0 + i] * W[(size_t)(k0 + i) * Hd + col];
    partial[kg][c] = acc;
    __syncthreads();

    if (t < 32) {
        float s = partial[0][t];
        #pragma unroll
        for (int j = 1; j < 16; ++j) s += partial[j][t];
        v[b * Hd + hc * 32 + t] = s;
    }
}

// ---------------------------------------------------------------------------
// K2: e[b,s] = enc[b,s,:] . v[b,:]  + per-WAVE (max, sum-exp) partial.
// grid (SB, Bn), block 256 (4 waves); 8 rows per wave.
// Marginal cost measured (R8 probe): 19.78 us for the 134 MB enc stream
// = ~6.8-7.5 TB/s effective -> at the memory-system read ceiling
// (occupancy pin, NT-hint, and load-front-loading variants all null/worse).
// ---------------------------------------------------------------------------
__global__ __launch_bounds__(256, 8) void k_energy(const float* __restrict__ enc,
                                                   const float* __restrict__ v,
                                                   float* __restrict__ e,
                                                   float2* __restrict__ partials) {
    const int sb   = blockIdx.x;
    const int b    = blockIdx.y;
    const int wave = threadIdx.x >> 6, lane = threadIdx.x & 63;

    const f32x4* vp = (const f32x4*)(v + b * Hd);
    const f32x4 v0 = vp[lane];
    const f32x4 v1 = vp[64 + lane];

    const int row0 = sb * 32 + wave * 8;
    const f32x4* base = (const f32x4*)(enc + ((size_t)b * Sn + row0) * Hd);

    float wA, wB;
    #pragma unroll
    for (int g = 0; g < 2; ++g) {
        const int rb = g * 4;
        float p[4];
        #pragma unroll
        for (int r = 0; r < 4; ++r) {
            const f32x4* rowp = base + (size_t)(rb + r) * (Hd / 4);
            const f32x4 a0 = __builtin_nontemporal_load(rowp + lane);
            const f32x4 a1 = __builtin_nontemporal_load(rowp + 64 + lane);
            p[r] = a0.x * v0.x + a0.y * v0.y + a0.z * v0.z + a0.w * v0.w
                 + a1.x * v1.x + a1.y * v1.y + a1.z * v1.z + a1.w * v1.w;
        }
        // packed reduce: after this, lane l (l<4) holds full sum of row rb+l
        float s0 = p[0] + __shfl_xor(p[0], 1, 64);
        float s1 = p[1] + __shfl_xor(p[1], 1, 64);
        float s2 = p[2] + __shfl_xor(p[2], 1, 64);
        float s3 = p[3] + __shfl_xor(p[3], 1, 64);
        float t0 = (lane & 1) ? s1 : s0;
        float t1 = (lane & 1) ? s3 : s2;
        t0 += __shfl_xor(t0, 2, 64);
        t1 += __shfl_xor(t1, 2, 64);
        float w = (lane & 2) ? t1 : t0;
        w += __shfl_xor(w, 4, 64);
        w += __shfl_xor(w, 8, 64);
        w += __shfl_xor(w, 16, 64);
        w += __shfl_xor(w, 32, 64);
        if (g == 0) wA = w; else wB = w;
    }

    // per-wave stats: rows replicated every 4 lanes -> offsets 1,2 suffice
    float m = fmaxf(wA, wB);
    m = fmaxf(m, __shfl_xor(m, 1, 64));
    m = fmaxf(m, __shfl_xor(m, 2, 64));
    float s = __expf(wA - m) + __expf(wB - m);
    s += __shfl_xor(s, 1, 64);
    s += __shfl_xor(s, 2, 64);

    if (lane < 8) e[(size_t)b * Sn + row0 + lane] = (lane < 4) ? wA : wB;
    if (lane == 0) partials[(size_t)b * PW + sb * 4 + wave] = make_float2(m, s);
}

// ---------------------------------------------------------------------------
// K3: out[b,j] = exp(e[b,j] - M_b) / L_b.  grid (16, Bn), block 512.
// Each lane loads 16 of the 1024 partials, register-tree LSE merge (depth 4),
// then a 6-step butterfly across the wave.
// ---------------------------------------------------------------------------
__global__ __launch_bounds__(512) void k_finalize(const float* __restrict__ e,
                                                  const float2* __restrict__ partials,
                                                  float* __restrict__ out) {
    const int b    = blockIdx.y;
    const int t    = threadIdx.x;
    const int lane = t & 63;

    const float2* pp = partials + (size_t)b * PW;
    float m[16], l[16];
    #pragma unroll
    for (int i = 0; i < 16; ++i) {
        const float2 q = pp[lane + 64 * i];
        m[i] = q.x; l[i] = q.y;
    }
    #pragma unroll
    for (int st = 8; st >= 1; st >>= 1) {
        #pragma unroll
        for (int i = 0; i < st; ++i) {
            const float Mn = fmaxf(m[i], m[i + st]);
            l[i] = l[i] * __expf(m[i] - Mn) + l[i + st] * __expf(m[i + st] - Mn);
            m[i] = Mn;
        }
    }
    float M = m[0], L = l[0];
    #pragma unroll
    for (int off = 32; off >= 1; off >>= 1) {
        const float Mo = __shfl_xor(M, off, 64);
        const float Lo = __shfl_xor(L, off, 64);
        const float Mn = fmaxf(M, Mo);
        L = L * __expf(M - Mn) + Lo * __expf(Mo - Mn);
        M = Mn;
    }
    const float inv = 1.0f / L;

    const size_t j = (size_t)b * Sn + blockIdx.x * 512 + t;
    out[j] = __expf(e[j] - M) * inv;
}

// ---------------------------------------------------------------------------
extern "C" void kernel_launch(void* const* d_in, const int* in_sizes, int n_in,
                              void* d_out, int out_size, void* d_ws, size_t ws_size,
                              hipStream_t stream) {
    const float* hidden = (const float*)d_in[0];   // [1,B,H]
    const float* enc    = (const float*)d_in[1];   // [B,S,H]
    const float* W      = (const float*)d_in[2];   // [H,H]
    // d_in[3] (bias) unused: softmax over s is shift-invariant; bias adds a
    // per-b constant c[b] = bias . h[b] that cancels.
    float* out = (float*)d_out;                    // [B,S] f32

    float*  v        = (float*)d_ws;               // Bn*Hd floats (16 KB)
    float2* partials = (float2*)(v + Bn * Hd);     // Bn*PW float2 (64 KB)
    float*  e        = (float*)(partials + (size_t)Bn * PW); // Bn*Sn floats

    k_proj    <<<dim3(16, Bn), 512, 0, stream>>>(hidden, W, v);
    k_energy  <<<dim3(SB, Bn), 256, 0, stream>>>(enc, v, e, partials);
    k_finalize<<<dim3(16, Bn), 512, 0, stream>>>(e, partials, out);
}